// Round 2
// baseline (1596.948 us; speedup 1.0000x reference)
//
#include <hip/hip_runtime.h>
#include <hip/hip_bf16.h>

#define IN_DIM 128
#define HID 64

typedef __hip_bfloat16 bf16;

// generic element load: is_f32 ? fp32 : bf16 (element-indexed, so host never
// needs to know the element size)
__device__ __forceinline__ float loadf(const void* p, size_t i, int isf) {
    if (isf) return ((const float*)p)[i];
    unsigned int u = ((const unsigned short*)p)[i];
    union { unsigned int b; float f; } c;
    c.b = u << 16;
    return c.f;
}

// ---------------- dtype detector ----------------
// Read first 256 bytes of feats as bf16. True bf16 N(0,1): no |x|>=2^14.
// fp32 read as bf16: low half-words are mantissa garbage -> ~44% have
// exponent >= 141 (|x|>=16384) or NaN/Inf. flag=1 means fp32.
__global__ void detect_kernel(const unsigned short* __restrict__ feats, int* flag) {
    int lane = threadIdx.x;  // 64 threads
    int bad = 0;
    for (int j = lane; j < 128; j += 64) {
        unsigned short u = feats[j];
        int expo = (u >> 7) & 0xFF;
        if (expo >= 141) bad = 1;
    }
    unsigned long long m = __ballot(bad);
    if (lane == 0) *flag = (__popcll(m) > 4) ? 1 : 0;
}

// ---------------- zero int buffer ----------------
__global__ void zero_kernel(int* __restrict__ p, int n) {
    int i = blockIdx.x * blockDim.x + threadIdx.x;
    int stride = gridDim.x * blockDim.x;
    for (; i < n; i += stride) p[i] = 0;
}

// ---------------- degree count ----------------
__global__ void degree_kernel(const int* __restrict__ src, const int* __restrict__ dst,
                              int* deg_out, int* deg_in, int E) {
    int i = blockIdx.x * blockDim.x + threadIdx.x;
    if (i < E) {
        atomicAdd(&deg_out[src[i]], 1);
        atomicAdd(&deg_in[dst[i]], 1);
    }
}

// ---------------- single-block exclusive scan of deg_in -> row_start, cursor ----------------
__global__ __launch_bounds__(256) void scan_kernel(const int* __restrict__ deg_in,
                                                   int* __restrict__ row_start,
                                                   int* __restrict__ cursor, int N) {
    __shared__ int part[256];
    int tid = threadIdx.x;
    int chunk = (N + 255) >> 8;
    int b = tid * chunk;
    int e = min(b + chunk, N);
    int s = 0;
    for (int i = b; i < e; ++i) s += deg_in[i];
    part[tid] = s;
    __syncthreads();
    for (int off = 1; off < 256; off <<= 1) {
        int add = (tid >= off) ? part[tid - off] : 0;
        __syncthreads();
        part[tid] += add;
        __syncthreads();
    }
    int run = (tid == 0) ? 0 : part[tid - 1];
    for (int i = b; i < e; ++i) {
        row_start[i] = run;
        cursor[i] = run;
        run += deg_in[i];
    }
    if (tid == 255) row_start[N] = part[255];
}

// ---------------- CSR fill (edges bucketed by dst) ----------------
__global__ void csr_fill_kernel(const int* __restrict__ src, const int* __restrict__ dst,
                                int* cursor, int* __restrict__ csr_src, int E) {
    int i = blockIdx.x * blockDim.x + threadIdx.x;
    if (i < E) {
        int pos = atomicAdd(&cursor[dst[i]], 1);
        csr_src[pos] = src[i];
    }
}

// ---------------- y1 = (x @ W1) * norm_src   [N,64] ----------------
// 256 threads = 4 waves; 64 nodes per block; wave-per-node, lane = out feature
__global__ __launch_bounds__(256) void xw1_kernel(const void* __restrict__ feats, size_t xoff,
                                                  const void* __restrict__ W1,
                                                  const int* __restrict__ deg_out,
                                                  const int* __restrict__ flag,
                                                  float* __restrict__ y1, int N) {
    __shared__ float W1s[IN_DIM * HID];  // 32 KB
    __shared__ float xs[4][IN_DIM];
    int isf = *flag;
    int tid = threadIdx.x;
    for (int i = tid; i < IN_DIM * HID; i += 256) W1s[i] = loadf(W1, i, isf);
    __syncthreads();
    int wave = tid >> 6, lane = tid & 63;
    int base0 = blockIdx.x * 64;
    for (int it = 0; it < 16; ++it) {
        int n = base0 + wave * 16 + it;
        if (n < N) {
            size_t ro = xoff + (size_t)n * IN_DIM;
            xs[wave][2 * lane]     = loadf(feats, ro + 2 * lane, isf);
            xs[wave][2 * lane + 1] = loadf(feats, ro + 2 * lane + 1, isf);
            // same-wave LDS RAW: hardware/compiler orders ds ops within a wave
            float acc = 0.f;
#pragma unroll 16
            for (int k = 0; k < IN_DIM; ++k) acc = fmaf(xs[wave][k], W1s[k * HID + lane], acc);
            float ns = rsqrtf(fmaxf((float)deg_out[n], 1.f));
            y1[(size_t)n * HID + lane] = acc * ns;
        }
    }
}

// ---------------- layer1: aggregate + relu + (@W2)*norm_src -> y2 ----------------
__global__ __launch_bounds__(256) void agg1_w2_kernel(const float* __restrict__ y1,
                                                      const void* __restrict__ W2,
                                                      const void* __restrict__ b1,
                                                      const int* __restrict__ row_start,
                                                      const int* __restrict__ csr_src,
                                                      const int* __restrict__ deg_out,
                                                      const int* __restrict__ flag,
                                                      float* __restrict__ y2, int N) {
    __shared__ float W2s[HID * HID];  // 16 KB
    __shared__ float hs[4][HID];
    int isf = *flag;
    int tid = threadIdx.x;
    int wave = tid >> 6, lane = tid & 63;
    for (int i = tid; i < HID * HID; i += 256) W2s[i] = loadf(W2, i, isf);
    float b1l = loadf(b1, lane, isf);
    __syncthreads();
    for (int n = blockIdx.x * 4 + wave; n < N; n += gridDim.x * 4) {
        int rs = row_start[n];
        int re = row_start[n + 1];
        float acc = 0.f;
        for (int e2 = rs; e2 < re; ++e2) {
            int s = csr_src[e2];
            acc += y1[(size_t)s * HID + lane];  // coalesced 256B row
        }
        float nd = rsqrtf(fmaxf((float)(re - rs), 1.f));
        hs[wave][lane] = fmaxf(fmaf(acc, nd, b1l), 0.f);  // relu(agg*nd + b1)
        float acc2 = 0.f;
#pragma unroll
        for (int k = 0; k < HID; ++k) acc2 = fmaf(hs[wave][k], W2s[k * HID + lane], acc2);
        float ns = rsqrtf(fmaxf((float)deg_out[n], 1.f));
        y2[(size_t)n * HID + lane] = acc2 * ns;
    }
}

// ---------------- layer2: aggregate + bias, then u = h@W3_top, v = h@W3_bot ----------------
__global__ __launch_bounds__(256) void agg2_w3_kernel(const float* __restrict__ y2,
                                                      const void* __restrict__ W3,
                                                      const void* __restrict__ b2,
                                                      const int* __restrict__ row_start,
                                                      const int* __restrict__ csr_src,
                                                      const int* __restrict__ flag,
                                                      float* __restrict__ u,
                                                      float* __restrict__ v, int N) {
    __shared__ float W3s[2 * HID * HID];  // 32 KB
    __shared__ float hs[4][HID];
    int isf = *flag;
    int tid = threadIdx.x;
    int wave = tid >> 6, lane = tid & 63;
    for (int i = tid; i < 2 * HID * HID; i += 256) W3s[i] = loadf(W3, i, isf);
    float b2l = loadf(b2, lane, isf);
    __syncthreads();
    for (int n = blockIdx.x * 4 + wave; n < N; n += gridDim.x * 4) {
        int rs = row_start[n];
        int re = row_start[n + 1];
        float acc = 0.f;
        for (int e2 = rs; e2 < re; ++e2) {
            int s = csr_src[e2];
            acc += y2[(size_t)s * HID + lane];
        }
        float nd = rsqrtf(fmaxf((float)(re - rs), 1.f));
        hs[wave][lane] = fmaf(acc, nd, b2l);  // layer2: no relu
        float au = 0.f, av = 0.f;
#pragma unroll
        for (int k = 0; k < HID; ++k) {
            float h = hs[wave][k];
            au = fmaf(h, W3s[k * HID + lane], au);
            av = fmaf(h, W3s[(HID + k) * HID + lane], av);
        }
        u[(size_t)n * HID + lane] = au;
        v[(size_t)n * HID + lane] = av;
    }
}

// ---------------- per-edge scorer: relu(u[s]+v[d]+b3) . W4 + b4 ----------------
__global__ __launch_bounds__(256) void score_kernel(const float* __restrict__ u,
                                                    const float* __restrict__ v,
                                                    const int* __restrict__ sn,
                                                    const int* __restrict__ dn,
                                                    const void* __restrict__ b3,
                                                    const void* __restrict__ W4,
                                                    const void* __restrict__ b4,
                                                    const int* __restrict__ flag,
                                                    void* __restrict__ out, int E) {
    int isf = *flag;
    int tid = threadIdx.x;
    int lane = tid & 63;
    int gw = (blockIdx.x * 256 + tid) >> 6;  // global wave id
    int nw = gridDim.x * 4;
    float b3l = loadf(b3, lane, isf);
    float w4l = loadf(W4, lane, isf);
    float b4v = loadf(b4, 0, isf);
    for (int i = gw; i < E; i += nw) {
        int s = sn[i], d = dn[i];
        float h = fmaxf(u[(size_t)s * HID + lane] + v[(size_t)d * HID + lane] + b3l, 0.f);
        float p = h * w4l;
#pragma unroll
        for (int off = 32; off > 0; off >>= 1) p += __shfl_xor(p, off, 64);
        if (lane == 0) {
            float r = p + b4v;
            if (isf) ((float*)out)[i] = r;
            else     ((bf16*)out)[i] = __float2bfloat16(r);
        }
    }
}

extern "C" void kernel_launch(void* const* d_in, const int* in_sizes, int n_in,
                              void* d_out, int out_size, void* d_ws, size_t ws_size,
                              hipStream_t stream) {
    const void* feats = d_in[0];
    const void* W1 = d_in[1];
    const void* b1 = d_in[2];
    const void* W2 = d_in[3];
    const void* b2 = d_in[4];
    const void* W3 = d_in[5];
    const void* b3 = d_in[6];
    const void* W4 = d_in[7];
    const void* b4 = d_in[8];
    const int* src_seq = (const int*)d_in[9];
    const int* dst_seq = (const int*)d_in[10];
    const int* src_next = (const int*)d_in[11];
    const int* dst_next = (const int*)d_in[12];

    const int E = in_sizes[11];                // src_next
    const int N = in_sizes[0] / (3 * IN_DIM);  // feats = [T=3, N, 128]
    const int T = in_sizes[9] / E;             // 3

    // only the last snapshot matters: h = h_seq[-1]
    const size_t xoff = (size_t)(T - 1) * N * IN_DIM;  // element offset into feats
    const int* src = src_seq + (size_t)(T - 1) * E;
    const int* dst = dst_seq + (size_t)(T - 1) * E;

    // workspace carve-out (all buffers fully written before read)
    char* w = (char*)d_ws;
    auto alloc = [&](size_t bytes) {
        void* p = (void*)w;
        w += (bytes + 255) & ~(size_t)255;
        return p;
    };
    int* flag      = (int*)alloc(4);
    int* deg_out   = (int*)alloc((size_t)N * 4);
    int* deg_in    = (int*)alloc((size_t)N * 4);
    int* row_start = (int*)alloc((size_t)(N + 1) * 4);
    int* cursor    = (int*)alloc((size_t)N * 4);
    int* csr_src   = (int*)alloc((size_t)E * 4);
    float* y1      = (float*)alloc((size_t)N * HID * 4);
    float* y2      = (float*)alloc((size_t)N * HID * 4);
    float* vv      = (float*)alloc((size_t)N * HID * 4);
    float* uu      = y1;  // y1 dead after agg1_w2; reuse as u

    detect_kernel<<<1, 64, 0, stream>>>((const unsigned short*)feats, flag);
    zero_kernel<<<512, 256, 0, stream>>>(deg_out, N);
    zero_kernel<<<512, 256, 0, stream>>>(deg_in, N);
    degree_kernel<<<(E + 255) / 256, 256, 0, stream>>>(src, dst, deg_out, deg_in, E);
    scan_kernel<<<1, 256, 0, stream>>>(deg_in, row_start, cursor, N);
    csr_fill_kernel<<<(E + 255) / 256, 256, 0, stream>>>(src, dst, cursor, csr_src, E);
    xw1_kernel<<<(N + 63) / 64, 256, 0, stream>>>(feats, xoff, W1, deg_out, flag, y1, N);
    agg1_w2_kernel<<<2048, 256, 0, stream>>>(y1, W2, b1, row_start, csr_src, deg_out, flag, y2, N);
    agg2_w3_kernel<<<2048, 256, 0, stream>>>(y2, W3, b2, row_start, csr_src, flag, uu, vv, N);
    score_kernel<<<4096, 256, 0, stream>>>(uu, vv, src_next, dst_next, b3, W4, b4, flag,
                                           (void*)d_out, E);
}

// Round 3
// 1191.147 us; speedup vs baseline: 1.3407x; 1.3407x over previous
//
#include <hip/hip_runtime.h>
#include <hip/hip_bf16.h>

#define IN_DIM 128
#define HID 64

typedef __hip_bfloat16 bf16;

// generic element load: is_f32 ? fp32 : bf16 (element-indexed)
__device__ __forceinline__ float loadf(const void* p, size_t i, int isf) {
    if (isf) return ((const float*)p)[i];
    unsigned int u = ((const unsigned short*)p)[i];
    union { unsigned int b; float f; } c;
    c.b = u << 16;
    return c.f;
}

// ---------------- dtype detector (flag=1 means fp32 buffers) ----------------
__global__ void detect_kernel(const unsigned short* __restrict__ feats, int* flag) {
    int lane = threadIdx.x;  // 64 threads
    int bad = 0;
    for (int j = lane; j < 128; j += 64) {
        unsigned short u = feats[j];
        int expo = (u >> 7) & 0xFF;
        if (expo >= 141) bad = 1;
    }
    unsigned long long m = __ballot(bad);
    if (lane == 0) *flag = (__popcll(m) > 4) ? 1 : 0;
}

// ---------------- zero int buffer ----------------
__global__ void zero_kernel(int* __restrict__ p, int n) {
    int i = blockIdx.x * blockDim.x + threadIdx.x;
    int stride = gridDim.x * blockDim.x;
    for (; i < n; i += stride) p[i] = 0;
}

// ---------------- degree count ----------------
__global__ void degree_kernel(const int* __restrict__ src, const int* __restrict__ dst,
                              int* deg_out, int* deg_in, int E) {
    int i = blockIdx.x * blockDim.x + threadIdx.x;
    if (i < E) {
        atomicAdd(&deg_out[src[i]], 1);
        atomicAdd(&deg_in[dst[i]], 1);
    }
}

// ---------------- single-block exclusive scan of deg_in -> row_start, cursor ----------------
__global__ __launch_bounds__(1024) void scan_kernel(const int* __restrict__ deg_in,
                                                    int* __restrict__ row_start,
                                                    int* __restrict__ cursor, int N) {
    __shared__ int part[1024];
    int tid = threadIdx.x;
    int chunk = (N + 1023) >> 10;
    int b = tid * chunk;
    int e = min(b + chunk, N);
    int s = 0;
    for (int i = b; i < e; ++i) s += deg_in[i];
    part[tid] = s;
    __syncthreads();
    for (int off = 1; off < 1024; off <<= 1) {
        int add = (tid >= off) ? part[tid - off] : 0;
        __syncthreads();
        part[tid] += add;
        __syncthreads();
    }
    int run = (tid == 0) ? 0 : part[tid - 1];
    for (int i = b; i < e; ++i) {
        row_start[i] = run;
        cursor[i] = run;
        run += deg_in[i];
    }
    if (tid == 1023) row_start[N] = part[1023];
}

// ---------------- CSR fill (edges bucketed by dst) ----------------
__global__ void csr_fill_kernel(const int* __restrict__ src, const int* __restrict__ dst,
                                int* cursor, int* __restrict__ csr_src, int E) {
    int i = blockIdx.x * blockDim.x + threadIdx.x;
    if (i < E) {
        int pos = atomicAdd(&cursor[dst[i]], 1);
        csr_src[pos] = src[i];
    }
}

// ---------------- y1 = (x @ W1) * norm_src   [N,64] ----------------
__global__ __launch_bounds__(256) void xw1_kernel(const void* __restrict__ feats, size_t xoff,
                                                  const void* __restrict__ W1,
                                                  const int* __restrict__ deg_out,
                                                  const int* __restrict__ flag,
                                                  float* __restrict__ y1, int N) {
    __shared__ float W1s[IN_DIM * HID];  // 32 KB
    __shared__ float xs[4][IN_DIM];
    int isf = *flag;
    int tid = threadIdx.x;
    for (int i = tid; i < IN_DIM * HID; i += 256) W1s[i] = loadf(W1, i, isf);
    __syncthreads();
    int wave = tid >> 6, lane = tid & 63;
    int base0 = blockIdx.x * 64;
    for (int it = 0; it < 16; ++it) {
        int n = base0 + wave * 16 + it;
        if (n < N) {
            size_t ro = xoff + (size_t)n * IN_DIM;
            xs[wave][2 * lane]     = loadf(feats, ro + 2 * lane, isf);
            xs[wave][2 * lane + 1] = loadf(feats, ro + 2 * lane + 1, isf);
            float acc = 0.f;
#pragma unroll 16
            for (int k = 0; k < IN_DIM; ++k) acc = fmaf(xs[wave][k], W1s[k * HID + lane], acc);
            float ns = rsqrtf(fmaxf((float)deg_out[n], 1.f));
            y1[(size_t)n * HID + lane] = acc * ns;
        }
    }
}

// masked 8-wide gather-accumulate over one CSR row; indices are wave-uniform
// (scalar loads) and 8 row gathers stay in flight simultaneously.
__device__ __forceinline__ float row_aggregate(const float* __restrict__ y,
                                               const int* __restrict__ csr_src,
                                               int rs, int re, int lane) {
    float acc = 0.f;
    for (int base_e = rs; base_e < re; base_e += 8) {
#pragma unroll
        for (int j = 0; j < 8; ++j) {
            int ee = base_e + j;
            int ec = min(ee, re - 1);          // uniform clamp, safe addr
            int s = csr_src[ec];               // s_load (wave-uniform)
            float a = y[(size_t)s * HID + lane];
            acc += (ee < re) ? a : 0.f;
        }
    }
    return acc;
}

// ---------------- layer1: aggregate + relu + (@W2)*norm_src -> y2 ----------------
__global__ __launch_bounds__(256) void agg1_w2_kernel(const float* __restrict__ y1,
                                                      const void* __restrict__ W2,
                                                      const void* __restrict__ b1,
                                                      const int* __restrict__ row_start,
                                                      const int* __restrict__ csr_src,
                                                      const int* __restrict__ deg_out,
                                                      const int* __restrict__ flag,
                                                      float* __restrict__ y2, int N) {
    __shared__ float W2s[HID * HID];  // 16 KB
    __shared__ float hs[4][HID];
    int isf = *flag;
    int tid = threadIdx.x;
    int wave = tid >> 6, lane = tid & 63;
    for (int i = tid; i < HID * HID; i += 256) W2s[i] = loadf(W2, i, isf);
    float b1l = loadf(b1, lane, isf);
    __syncthreads();
    for (int n = blockIdx.x * 4 + wave; n < N; n += gridDim.x * 4) {
        int nu = __builtin_amdgcn_readfirstlane(n);
        int rs = row_start[nu];
        int re = row_start[nu + 1];
        float acc = row_aggregate(y1, csr_src, rs, re, lane);
        float nd = rsqrtf(fmaxf((float)(re - rs), 1.f));
        hs[wave][lane] = fmaxf(fmaf(acc, nd, b1l), 0.f);  // relu(agg*nd + b1)
        float acc2 = 0.f;
#pragma unroll
        for (int k = 0; k < HID; ++k) acc2 = fmaf(hs[wave][k], W2s[k * HID + lane], acc2);
        float ns = rsqrtf(fmaxf((float)deg_out[nu], 1.f));
        y2[(size_t)nu * HID + lane] = acc2 * ns;
    }
}

// ---------------- layer2: aggregate + bias, then u = h@W3_top, v = h@W3_bot ----------------
__global__ __launch_bounds__(256) void agg2_w3_kernel(const float* __restrict__ y2,
                                                      const void* __restrict__ W3,
                                                      const void* __restrict__ b2,
                                                      const int* __restrict__ row_start,
                                                      const int* __restrict__ csr_src,
                                                      const int* __restrict__ flag,
                                                      float* __restrict__ u,
                                                      float* __restrict__ v, int N) {
    __shared__ float W3s[2 * HID * HID];  // 32 KB
    __shared__ float hs[4][HID];
    int isf = *flag;
    int tid = threadIdx.x;
    int wave = tid >> 6, lane = tid & 63;
    for (int i = tid; i < 2 * HID * HID; i += 256) W3s[i] = loadf(W3, i, isf);
    float b2l = loadf(b2, lane, isf);
    __syncthreads();
    for (int n = blockIdx.x * 4 + wave; n < N; n += gridDim.x * 4) {
        int nu = __builtin_amdgcn_readfirstlane(n);
        int rs = row_start[nu];
        int re = row_start[nu + 1];
        float acc = row_aggregate(y2, csr_src, rs, re, lane);
        float nd = rsqrtf(fmaxf((float)(re - rs), 1.f));
        hs[wave][lane] = fmaf(acc, nd, b2l);  // layer2: no relu
        float au = 0.f, av = 0.f;
#pragma unroll
        for (int k = 0; k < HID; ++k) {
            float h = hs[wave][k];
            au = fmaf(h, W3s[k * HID + lane], au);
            av = fmaf(h, W3s[(HID + k) * HID + lane], av);
        }
        u[(size_t)nu * HID + lane] = au;
        v[(size_t)nu * HID + lane] = av;
    }
}

// ---------------- per-edge scorer: relu(u[s]+v[d]+b3) . W4 + b4 ----------------
__global__ __launch_bounds__(256) void score_kernel(const float* __restrict__ u,
                                                    const float* __restrict__ v,
                                                    const int* __restrict__ sn,
                                                    const int* __restrict__ dn,
                                                    const void* __restrict__ b3,
                                                    const void* __restrict__ W4,
                                                    const void* __restrict__ b4,
                                                    const int* __restrict__ flag,
                                                    void* __restrict__ out, int E) {
    int isf = *flag;
    int tid = threadIdx.x;
    int lane = tid & 63;
    int gw = __builtin_amdgcn_readfirstlane((blockIdx.x * 256 + tid) >> 6);
    int nw = gridDim.x * 4;
    float b3l = loadf(b3, lane, isf);
    float w4l = loadf(W4, lane, isf);
    float b4v = loadf(b4, 0, isf);
    int i = gw;
    // 4-way unrolled: 8 independent 256B gathers in flight per wave
    for (; i + 3 * nw < E; i += 4 * nw) {
        int i0 = i, i1 = i + nw, i2 = i + 2 * nw, i3 = i + 3 * nw;
        int s0 = sn[i0], d0 = dn[i0];
        int s1 = sn[i1], d1 = dn[i1];
        int s2 = sn[i2], d2 = dn[i2];
        int s3 = sn[i3], d3 = dn[i3];
        float us0 = u[(size_t)s0 * HID + lane], vd0 = v[(size_t)d0 * HID + lane];
        float us1 = u[(size_t)s1 * HID + lane], vd1 = v[(size_t)d1 * HID + lane];
        float us2 = u[(size_t)s2 * HID + lane], vd2 = v[(size_t)d2 * HID + lane];
        float us3 = u[(size_t)s3 * HID + lane], vd3 = v[(size_t)d3 * HID + lane];
        float p0 = fmaxf(us0 + vd0 + b3l, 0.f) * w4l;
        float p1 = fmaxf(us1 + vd1 + b3l, 0.f) * w4l;
        float p2 = fmaxf(us2 + vd2 + b3l, 0.f) * w4l;
        float p3 = fmaxf(us3 + vd3 + b3l, 0.f) * w4l;
#pragma unroll
        for (int off = 32; off > 0; off >>= 1) {
            p0 += __shfl_xor(p0, off, 64);
            p1 += __shfl_xor(p1, off, 64);
            p2 += __shfl_xor(p2, off, 64);
            p3 += __shfl_xor(p3, off, 64);
        }
        if (lane == 0) {
            if (isf) {
                ((float*)out)[i0] = p0 + b4v; ((float*)out)[i1] = p1 + b4v;
                ((float*)out)[i2] = p2 + b4v; ((float*)out)[i3] = p3 + b4v;
            } else {
                ((bf16*)out)[i0] = __float2bfloat16(p0 + b4v);
                ((bf16*)out)[i1] = __float2bfloat16(p1 + b4v);
                ((bf16*)out)[i2] = __float2bfloat16(p2 + b4v);
                ((bf16*)out)[i3] = __float2bfloat16(p3 + b4v);
            }
        }
    }
    for (; i < E; i += nw) {
        int s = sn[i], d = dn[i];
        float h = fmaxf(u[(size_t)s * HID + lane] + v[(size_t)d * HID + lane] + b3l, 0.f);
        float p = h * w4l;
#pragma unroll
        for (int off = 32; off > 0; off >>= 1) p += __shfl_xor(p, off, 64);
        if (lane == 0) {
            float r = p + b4v;
            if (isf) ((float*)out)[i] = r;
            else     ((bf16*)out)[i] = __float2bfloat16(r);
        }
    }
}

extern "C" void kernel_launch(void* const* d_in, const int* in_sizes, int n_in,
                              void* d_out, int out_size, void* d_ws, size_t ws_size,
                              hipStream_t stream) {
    const void* feats = d_in[0];
    const void* W1 = d_in[1];
    const void* b1 = d_in[2];
    const void* W2 = d_in[3];
    const void* b2 = d_in[4];
    const void* W3 = d_in[5];
    const void* b3 = d_in[6];
    const void* W4 = d_in[7];
    const void* b4 = d_in[8];
    const int* src_seq = (const int*)d_in[9];
    const int* dst_seq = (const int*)d_in[10];
    const int* src_next = (const int*)d_in[11];
    const int* dst_next = (const int*)d_in[12];

    const int E = in_sizes[11];                // src_next
    const int N = in_sizes[0] / (3 * IN_DIM);  // feats = [T=3, N, 128]
    const int T = in_sizes[9] / E;             // 3

    // only the last snapshot matters: h = h_seq[-1]
    const size_t xoff = (size_t)(T - 1) * N * IN_DIM;  // element offset into feats
    const int* src = src_seq + (size_t)(T - 1) * E;
    const int* dst = dst_seq + (size_t)(T - 1) * E;

    char* w = (char*)d_ws;
    auto alloc = [&](size_t bytes) {
        void* p = (void*)w;
        w += (bytes + 255) & ~(size_t)255;
        return p;
    };
    int* flag      = (int*)alloc(4);
    int* deg_out   = (int*)alloc((size_t)N * 4);
    int* deg_in    = (int*)alloc((size_t)N * 4);
    int* row_start = (int*)alloc((size_t)(N + 1) * 4);
    int* cursor    = (int*)alloc((size_t)N * 4);
    int* csr_src   = (int*)alloc((size_t)E * 4);
    float* y1      = (float*)alloc((size_t)N * HID * 4);
    float* y2      = (float*)alloc((size_t)N * HID * 4);
    float* vv      = (float*)alloc((size_t)N * HID * 4);
    float* uu      = y1;  // y1 dead after agg1_w2; reuse as u

    detect_kernel<<<1, 64, 0, stream>>>((const unsigned short*)feats, flag);
    zero_kernel<<<512, 256, 0, stream>>>(deg_out, N);
    zero_kernel<<<512, 256, 0, stream>>>(deg_in, N);
    degree_kernel<<<(E + 255) / 256, 256, 0, stream>>>(src, dst, deg_out, deg_in, E);
    scan_kernel<<<1, 1024, 0, stream>>>(deg_in, row_start, cursor, N);
    csr_fill_kernel<<<(E + 255) / 256, 256, 0, stream>>>(src, dst, cursor, csr_src, E);
    xw1_kernel<<<(N + 63) / 64, 256, 0, stream>>>(feats, xoff, W1, deg_out, flag, y1, N);
    agg1_w2_kernel<<<2048, 256, 0, stream>>>(y1, W2, b1, row_start, csr_src, deg_out, flag, y2, N);
    agg2_w3_kernel<<<2048, 256, 0, stream>>>(y2, W3, b2, row_start, csr_src, flag, uu, vv, N);
    score_kernel<<<4096, 256, 0, stream>>>(uu, vv, src_next, dst_next, b3, W4, b4, flag,
                                           (void*)d_out, E);
}

// Round 4
// 975.899 us; speedup vs baseline: 1.6364x; 1.2206x over previous
//
#include <hip/hip_runtime.h>
#include <hip/hip_bf16.h>

#define IN_DIM 128
#define HID 64
#define SCAN_TILE 1024  // 256 threads x 4 elements

typedef __hip_bfloat16 bf16;

// generic element load: is_f32 ? fp32 : bf16 (element-indexed)
__device__ __forceinline__ float loadf(const void* p, size_t i, int isf) {
    if (isf) return ((const float*)p)[i];
    unsigned int u = ((const unsigned short*)p)[i];
    union { unsigned int b; float f; } c;
    c.b = u << 16;
    return c.f;
}

// ---------------- dtype detector (flag=1 means fp32 buffers) ----------------
__global__ void detect_kernel(const unsigned short* __restrict__ feats, int* flag) {
    int lane = threadIdx.x;  // 64 threads
    int bad = 0;
    for (int j = lane; j < 128; j += 64) {
        unsigned short u = feats[j];
        int expo = (u >> 7) & 0xFF;
        if (expo >= 141) bad = 1;
    }
    unsigned long long m = __ballot(bad);
    if (lane == 0) *flag = (__popcll(m) > 4) ? 1 : 0;
}

// ---------------- zero int buffer ----------------
__global__ void zero_kernel(int* __restrict__ p, int n) {
    int i = blockIdx.x * blockDim.x + threadIdx.x;
    int stride = gridDim.x * blockDim.x;
    for (; i < n; i += stride) p[i] = 0;
}

// ---------------- degree count ----------------
__global__ void degree_kernel(const int* __restrict__ src, const int* __restrict__ dst,
                              int* deg_out, int* deg_in, int E) {
    int i = blockIdx.x * blockDim.x + threadIdx.x;
    if (i < E) {
        atomicAdd(&deg_out[src[i]], 1);
        atomicAdd(&deg_in[dst[i]], 1);
    }
}

// ---------------- 3-phase device-wide exclusive scan of deg_in ----------------
// phase 1: per-block (1024-elem tile) local exclusive scan -> row_start, block total -> partials
__global__ __launch_bounds__(256) void scan1_kernel(const int* __restrict__ deg_in,
                                                    int* __restrict__ row_start,
                                                    int* __restrict__ partials, int N) {
    __shared__ int part[256];
    int tid = threadIdx.x;
    int base = blockIdx.x * SCAN_TILE + tid * 4;
    int v0 = (base + 0 < N) ? deg_in[base + 0] : 0;
    int v1 = (base + 1 < N) ? deg_in[base + 1] : 0;
    int v2 = (base + 2 < N) ? deg_in[base + 2] : 0;
    int v3 = (base + 3 < N) ? deg_in[base + 3] : 0;
    part[tid] = v0 + v1 + v2 + v3;
    __syncthreads();
    for (int off = 1; off < 256; off <<= 1) {
        int add = (tid >= off) ? part[tid - off] : 0;
        __syncthreads();
        part[tid] += add;
        __syncthreads();
    }
    int run = (tid == 0) ? 0 : part[tid - 1];
    if (base + 0 < N) row_start[base + 0] = run;
    run += v0;
    if (base + 1 < N) row_start[base + 1] = run;
    run += v1;
    if (base + 2 < N) row_start[base + 2] = run;
    run += v2;
    if (base + 3 < N) row_start[base + 3] = run;
    if (tid == 255) partials[blockIdx.x] = part[255];
}

// phase 2: single block scans the per-block partials (G <= 1024) -> exclusive offsets, total
__global__ __launch_bounds__(1024) void scan2_kernel(int* __restrict__ partials,
                                                     int* __restrict__ row_start,
                                                     int G, int N) {
    __shared__ int part[1024];
    int tid = threadIdx.x;
    int v = (tid < G) ? partials[tid] : 0;
    part[tid] = v;
    __syncthreads();
    for (int off = 1; off < 1024; off <<= 1) {
        int add = (tid >= off) ? part[tid - off] : 0;
        __syncthreads();
        part[tid] += add;
        __syncthreads();
    }
    if (tid < G) partials[tid] = (tid == 0) ? 0 : part[tid - 1];  // exclusive
    if (tid == 0) row_start[N] = part[1023];                      // total = E
}

// phase 3: add block offsets; mirror into cursor
__global__ __launch_bounds__(256) void scan3_kernel(const int* __restrict__ partials,
                                                    int* __restrict__ row_start,
                                                    int* __restrict__ cursor, int N) {
    int off = partials[blockIdx.x];
    int base = blockIdx.x * SCAN_TILE + threadIdx.x * 4;
#pragma unroll
    for (int j = 0; j < 4; ++j) {
        int idx = base + j;
        if (idx < N) {
            int r = row_start[idx] + off;
            row_start[idx] = r;
            cursor[idx] = r;
        }
    }
}

// ---------------- CSR fill (edges bucketed by dst) ----------------
__global__ void csr_fill_kernel(const int* __restrict__ src, const int* __restrict__ dst,
                                int* cursor, int* __restrict__ csr_src, int E) {
    int i = blockIdx.x * blockDim.x + threadIdx.x;
    if (i < E) {
        int pos = atomicAdd(&cursor[dst[i]], 1);
        csr_src[pos] = src[i];
    }
}

// ---------------- y1 = (x @ W1) * norm_src   [N,64] ----------------
__global__ __launch_bounds__(256) void xw1_kernel(const void* __restrict__ feats, size_t xoff,
                                                  const void* __restrict__ W1,
                                                  const int* __restrict__ deg_out,
                                                  const int* __restrict__ flag,
                                                  float* __restrict__ y1, int N) {
    __shared__ float W1s[IN_DIM * HID];  // 32 KB
    __shared__ float xs[4][IN_DIM];
    int isf = *flag;
    int tid = threadIdx.x;
    for (int i = tid; i < IN_DIM * HID; i += 256) W1s[i] = loadf(W1, i, isf);
    __syncthreads();
    int wave = tid >> 6, lane = tid & 63;
    int base0 = blockIdx.x * 64;
    for (int it = 0; it < 16; ++it) {
        int n = base0 + wave * 16 + it;
        if (n < N) {
            size_t ro = xoff + (size_t)n * IN_DIM;
            xs[wave][2 * lane]     = loadf(feats, ro + 2 * lane, isf);
            xs[wave][2 * lane + 1] = loadf(feats, ro + 2 * lane + 1, isf);
            float acc = 0.f;
#pragma unroll 16
            for (int k = 0; k < IN_DIM; ++k) acc = fmaf(xs[wave][k], W1s[k * HID + lane], acc);
            float ns = rsqrtf(fmaxf((float)deg_out[n], 1.f));
            y1[(size_t)n * HID + lane] = acc * ns;
        }
    }
}

// masked 8-wide gather-accumulate over one CSR row; indices are wave-uniform
// (scalar loads) and 8 row gathers stay in flight simultaneously.
__device__ __forceinline__ float row_aggregate(const float* __restrict__ y,
                                               const int* __restrict__ csr_src,
                                               int rs, int re, int lane) {
    float acc = 0.f;
    for (int base_e = rs; base_e < re; base_e += 8) {
#pragma unroll
        for (int j = 0; j < 8; ++j) {
            int ee = base_e + j;
            int ec = min(ee, re - 1);          // uniform clamp, safe addr
            int s = csr_src[ec];               // s_load (wave-uniform)
            float a = y[(size_t)s * HID + lane];
            acc += (ee < re) ? a : 0.f;
        }
    }
    return acc;
}

// ---------------- layer1: aggregate + relu + (@W2)*norm_src -> y2 ----------------
__global__ __launch_bounds__(256) void agg1_w2_kernel(const float* __restrict__ y1,
                                                      const void* __restrict__ W2,
                                                      const void* __restrict__ b1,
                                                      const int* __restrict__ row_start,
                                                      const int* __restrict__ csr_src,
                                                      const int* __restrict__ deg_out,
                                                      const int* __restrict__ flag,
                                                      float* __restrict__ y2, int N) {
    __shared__ float W2s[HID * HID];  // 16 KB
    __shared__ float hs[4][HID];
    int isf = *flag;
    int tid = threadIdx.x;
    int wave = tid >> 6, lane = tid & 63;
    for (int i = tid; i < HID * HID; i += 256) W2s[i] = loadf(W2, i, isf);
    float b1l = loadf(b1, lane, isf);
    __syncthreads();
    for (int n = blockIdx.x * 4 + wave; n < N; n += gridDim.x * 4) {
        int nu = __builtin_amdgcn_readfirstlane(n);
        int rs = row_start[nu];
        int re = row_start[nu + 1];
        float acc = row_aggregate(y1, csr_src, rs, re, lane);
        float nd = rsqrtf(fmaxf((float)(re - rs), 1.f));
        hs[wave][lane] = fmaxf(fmaf(acc, nd, b1l), 0.f);  // relu(agg*nd + b1)
        float acc2 = 0.f;
#pragma unroll
        for (int k = 0; k < HID; ++k) acc2 = fmaf(hs[wave][k], W2s[k * HID + lane], acc2);
        float ns = rsqrtf(fmaxf((float)deg_out[nu], 1.f));
        y2[(size_t)nu * HID + lane] = acc2 * ns;
    }
}

// ---------------- layer2: aggregate + bias, then u = h@W3_top, v = h@W3_bot ----------------
__global__ __launch_bounds__(256) void agg2_w3_kernel(const float* __restrict__ y2,
                                                      const void* __restrict__ W3,
                                                      const void* __restrict__ b2,
                                                      const int* __restrict__ row_start,
                                                      const int* __restrict__ csr_src,
                                                      const int* __restrict__ flag,
                                                      float* __restrict__ u,
                                                      float* __restrict__ v, int N) {
    __shared__ float W3s[2 * HID * HID];  // 32 KB
    __shared__ float hs[4][HID];
    int isf = *flag;
    int tid = threadIdx.x;
    int wave = tid >> 6, lane = tid & 63;
    for (int i = tid; i < 2 * HID * HID; i += 256) W3s[i] = loadf(W3, i, isf);
    float b2l = loadf(b2, lane, isf);
    __syncthreads();
    for (int n = blockIdx.x * 4 + wave; n < N; n += gridDim.x * 4) {
        int nu = __builtin_amdgcn_readfirstlane(n);
        int rs = row_start[nu];
        int re = row_start[nu + 1];
        float acc = row_aggregate(y2, csr_src, rs, re, lane);
        float nd = rsqrtf(fmaxf((float)(re - rs), 1.f));
        hs[wave][lane] = fmaf(acc, nd, b2l);  // layer2: no relu
        float au = 0.f, av = 0.f;
#pragma unroll
        for (int k = 0; k < HID; ++k) {
            float h = hs[wave][k];
            au = fmaf(h, W3s[k * HID + lane], au);
            av = fmaf(h, W3s[(HID + k) * HID + lane], av);
        }
        u[(size_t)nu * HID + lane] = au;
        v[(size_t)nu * HID + lane] = av;
    }
}

// ---------------- per-edge scorer: relu(u[s]+v[d]+b3) . W4 + b4 ----------------
__global__ __launch_bounds__(256) void score_kernel(const float* __restrict__ u,
                                                    const float* __restrict__ v,
                                                    const int* __restrict__ sn,
                                                    const int* __restrict__ dn,
                                                    const void* __restrict__ b3,
                                                    const void* __restrict__ W4,
                                                    const void* __restrict__ b4,
                                                    const int* __restrict__ flag,
                                                    void* __restrict__ out, int E) {
    int isf = *flag;
    int tid = threadIdx.x;
    int lane = tid & 63;
    int gw = __builtin_amdgcn_readfirstlane((blockIdx.x * 256 + tid) >> 6);
    int nw = gridDim.x * 4;
    float b3l = loadf(b3, lane, isf);
    float w4l = loadf(W4, lane, isf);
    float b4v = loadf(b4, 0, isf);
    int i = gw;
    // 4-way unrolled: 8 independent 256B gathers in flight per wave
    for (; i + 3 * nw < E; i += 4 * nw) {
        int i0 = i, i1 = i + nw, i2 = i + 2 * nw, i3 = i + 3 * nw;
        int s0 = sn[i0], d0 = dn[i0];
        int s1 = sn[i1], d1 = dn[i1];
        int s2 = sn[i2], d2 = dn[i2];
        int s3 = sn[i3], d3 = dn[i3];
        float us0 = u[(size_t)s0 * HID + lane], vd0 = v[(size_t)d0 * HID + lane];
        float us1 = u[(size_t)s1 * HID + lane], vd1 = v[(size_t)d1 * HID + lane];
        float us2 = u[(size_t)s2 * HID + lane], vd2 = v[(size_t)d2 * HID + lane];
        float us3 = u[(size_t)s3 * HID + lane], vd3 = v[(size_t)d3 * HID + lane];
        float p0 = fmaxf(us0 + vd0 + b3l, 0.f) * w4l;
        float p1 = fmaxf(us1 + vd1 + b3l, 0.f) * w4l;
        float p2 = fmaxf(us2 + vd2 + b3l, 0.f) * w4l;
        float p3 = fmaxf(us3 + vd3 + b3l, 0.f) * w4l;
#pragma unroll
        for (int off = 32; off > 0; off >>= 1) {
            p0 += __shfl_xor(p0, off, 64);
            p1 += __shfl_xor(p1, off, 64);
            p2 += __shfl_xor(p2, off, 64);
            p3 += __shfl_xor(p3, off, 64);
        }
        if (lane == 0) {
            if (isf) {
                ((float*)out)[i0] = p0 + b4v; ((float*)out)[i1] = p1 + b4v;
                ((float*)out)[i2] = p2 + b4v; ((float*)out)[i3] = p3 + b4v;
            } else {
                ((bf16*)out)[i0] = __float2bfloat16(p0 + b4v);
                ((bf16*)out)[i1] = __float2bfloat16(p1 + b4v);
                ((bf16*)out)[i2] = __float2bfloat16(p2 + b4v);
                ((bf16*)out)[i3] = __float2bfloat16(p3 + b4v);
            }
        }
    }
    for (; i < E; i += nw) {
        int s = sn[i], d = dn[i];
        float h = fmaxf(u[(size_t)s * HID + lane] + v[(size_t)d * HID + lane] + b3l, 0.f);
        float p = h * w4l;
#pragma unroll
        for (int off = 32; off > 0; off >>= 1) p += __shfl_xor(p, off, 64);
        if (lane == 0) {
            float r = p + b4v;
            if (isf) ((float*)out)[i] = r;
            else     ((bf16*)out)[i] = __float2bfloat16(r);
        }
    }
}

extern "C" void kernel_launch(void* const* d_in, const int* in_sizes, int n_in,
                              void* d_out, int out_size, void* d_ws, size_t ws_size,
                              hipStream_t stream) {
    const void* feats = d_in[0];
    const void* W1 = d_in[1];
    const void* b1 = d_in[2];
    const void* W2 = d_in[3];
    const void* b2 = d_in[4];
    const void* W3 = d_in[5];
    const void* b3 = d_in[6];
    const void* W4 = d_in[7];
    const void* b4 = d_in[8];
    const int* src_seq = (const int*)d_in[9];
    const int* dst_seq = (const int*)d_in[10];
    const int* src_next = (const int*)d_in[11];
    const int* dst_next = (const int*)d_in[12];

    const int E = in_sizes[11];                // src_next
    const int N = in_sizes[0] / (3 * IN_DIM);  // feats = [T=3, N, 128]
    const int T = in_sizes[9] / E;             // 3

    // only the last snapshot matters: h = h_seq[-1]
    const size_t xoff = (size_t)(T - 1) * N * IN_DIM;  // element offset into feats
    const int* src = src_seq + (size_t)(T - 1) * E;
    const int* dst = dst_seq + (size_t)(T - 1) * E;

    char* w = (char*)d_ws;
    auto alloc = [&](size_t bytes) {
        void* p = (void*)w;
        w += (bytes + 255) & ~(size_t)255;
        return p;
    };
    int* flag      = (int*)alloc(4);
    int* deg_out   = (int*)alloc((size_t)N * 4);
    int* deg_in    = (int*)alloc((size_t)N * 4);
    int* row_start = (int*)alloc((size_t)(N + 1) * 4);
    int* cursor    = (int*)alloc((size_t)N * 4);
    int* partials  = (int*)alloc(1024 * 4);
    int* csr_src   = (int*)alloc((size_t)E * 4);
    float* y1      = (float*)alloc((size_t)N * HID * 4);
    float* y2      = (float*)alloc((size_t)N * HID * 4);
    float* vv      = (float*)alloc((size_t)N * HID * 4);
    float* uu      = y1;  // y1 dead after agg1_w2; reuse as u

    const int G = (N + SCAN_TILE - 1) / SCAN_TILE;  // 98 for N=100K (must be <=1024)

    detect_kernel<<<1, 64, 0, stream>>>((const unsigned short*)feats, flag);
    zero_kernel<<<512, 256, 0, stream>>>(deg_out, N);
    zero_kernel<<<512, 256, 0, stream>>>(deg_in, N);
    degree_kernel<<<(E + 255) / 256, 256, 0, stream>>>(src, dst, deg_out, deg_in, E);
    scan1_kernel<<<G, 256, 0, stream>>>(deg_in, row_start, partials, N);
    scan2_kernel<<<1, 1024, 0, stream>>>(partials, row_start, G, N);
    scan3_kernel<<<G, 256, 0, stream>>>(partials, row_start, cursor, N);
    csr_fill_kernel<<<(E + 255) / 256, 256, 0, stream>>>(src, dst, cursor, csr_src, E);
    xw1_kernel<<<(N + 63) / 64, 256, 0, stream>>>(feats, xoff, W1, deg_out, flag, y1, N);
    agg1_w2_kernel<<<2048, 256, 0, stream>>>(y1, W2, b1, row_start, csr_src, deg_out, flag, y2, N);
    agg2_w3_kernel<<<2048, 256, 0, stream>>>(y2, W3, b2, row_start, csr_src, flag, uu, vv, N);
    score_kernel<<<4096, 256, 0, stream>>>(uu, vv, src_next, dst_next, b3, W4, b4, flag,
                                           (void*)d_out, E);
}